// Round 11
// baseline (188.891 us; speedup 1.0000x reference)
//
#include <hip/hip_runtime.h>
#include <hip/hip_bf16.h>
#include <math.h>

typedef __attribute__((ext_vector_type(8))) short short8;
typedef __attribute__((ext_vector_type(4))) short short4v;
typedef __attribute__((ext_vector_type(4))) float float4v;
typedef unsigned short ushort_t;

constexpr int NPTS = 32768;  // B*N
constexpr int NN   = 16384;  // points per batch
constexpr int KK   = 32;     // neighbors
constexpr int CC   = 128;    // channels
constexpr int GRP  = 8;      // points per block -> grid 4096 (2-wave blocks)
constexpr int SG   = 40;     // geo LDS row stride (shorts)
constexpr int SR   = 132;    // res LDS row stride (shorts)
#define LN_EPS 1e-5f

// d_ws layout (bytes)
constexpr size_t WS_WP   = 0;        // W' swizzled: 20*128*8 bf16 = 40960 B
constexpr size_t WS_WO   = 40960;    // w_out swizzled: 128*128 bf16 = 32768 B
constexpr size_t WS_BE   = 73728;    // beff: 128 f32 = 512 B
constexpr size_t WS_FB   = 79360;    // features bf16: 32768*128*2 = 8388608 B
constexpr size_t WS_NEED = WS_FB + (size_t)NPTS * CC * 2;

__device__ __forceinline__ short f2bs(float x) {
    return (short)__builtin_bit_cast(unsigned short, __float2bfloat16(x));
}
__device__ __forceinline__ float bs2f(ushort_t u) {
    return __uint_as_float(((unsigned)u) << 16);
}

// ---------------- single prep kernel (unchanged from R10) ----------------
__global__ __launch_bounds__(256) void prep_all(
    const float* __restrict__ features,
    const float* __restrict__ w_pos, const float* __restrict__ b_pos,
    const float* __restrict__ w_gcm, const float* __restrict__ b_gcm,
    const float* __restrict__ w_out,
    short* __restrict__ wsWp, short* __restrict__ wsWo, float* __restrict__ wsBeff,
    ushort_t* __restrict__ featbf, int do_convert)
{
    __shared__ float sPG[10 * 128];
    const int t = threadIdx.x, blk = blockIdx.x;

    if (blk < 512) {
        if (!do_convert) return;
        const int base = blk * 2048 + t;
        #pragma unroll
        for (int i = 0; i < 8; ++i) {
            const int f4 = base + i * 256;
            const float4 a = ((const float4*)features)[f4];
            short4v v; v[0]=f2bs(a.x); v[1]=f2bs(a.y); v[2]=f2bs(a.z); v[3]=f2bs(a.w);
            ((short4v*)featbf)[f4] = v;
        }
        return;
    }
    if (blk == 512) {          // W' k<128
        #pragma unroll 4
        for (int e = t; e < 16 * 128 * 8; e += 256) {
            const int j = e & 7, n = (e >> 3) & 127, g = e >> 10;
            wsWp[e] = f2bs(w_gcm[(g * 8 + j) * 128 + n]);
        }
        return;
    }
    if (blk == 513) {          // fold + W' tail
        const int c = t & 127, half = t >> 7;
        for (int gi = 0; gi < 5; ++gi) {
            const int g = gi * 2 + half;
            float s = 0.f;
            #pragma unroll
            for (int r = 0; r < 128; ++r) s += w_pos[g * 128 + r] * w_gcm[r * 128 + c];
            sPG[g * 128 + c] = s;
        }
        if (t < 128) {
            float s = b_gcm[t];
            #pragma unroll
            for (int r = 0; r < 128; ++r) s += b_pos[r] * w_gcm[r * 128 + t];
            wsBeff[t] = s;
        }
        __syncthreads();
        #pragma unroll 4
        for (int e2 = t; e2 < 4 * 128 * 8; e2 += 256) {
            const int e = 16 * 128 * 8 + e2;
            const int j = e & 7, n = (e >> 3) & 127, g = e >> 10;
            const int k = g * 8 + j;
            wsWp[e] = (k < 138) ? f2bs(sPG[(k - 128) * 128 + n]) : (short)0;
        }
        return;
    }
    // blk == 514: w_out swizzle
    #pragma unroll 4
    for (int e = t; e < 128 * 128; e += 256) {
        const int j = e & 7, n = (e >> 3) & 127, g = e >> 10;
        wsWo[e] = f2bs(w_out[(g * 8 + j) * 128 + n]);
    }
}

// ---------------- main: 2-wave blocks; wave = 64-col half; barrier couples only 2 waves ----------------
// LDS: sA 16384 + sG 5120 (epilogue-reused) + sRes 16*132*2=4224 + sIdx 512 = 26240 B -> 6 blocks/CU
template<int DMA>
__global__ __launch_bounds__(128) void bridge_main(
    const float* __restrict__ points, const float* __restrict__ features,
    const int*   __restrict__ gidx,
    const short* __restrict__ wsWp, const short* __restrict__ wsWo,
    const float* __restrict__ wsBeff, const ushort_t* __restrict__ featbf,
    const float* __restrict__ b_out, const float* __restrict__ ln_g,
    const float* __restrict__ ln_b,
    float* __restrict__ out)
{
    __shared__ short sA[2][KK * CC];      // staged tile, XOR-chunk-swizzled 256B rows
    __shared__ short sG[2][KK * SG];      // geo cols; epilogue: reused as sPS/sPQ
    __shared__ short sRes[16 * SR];       // 8 real rows + 8 zero rows (out-proj padding)
    __shared__ ushort_t sIdx[GRP * KK];   // 256 neighbor indices

    float* sPS = (float*)&sG[0][0];       // [2][16] (epilogue only)
    float* sPQ = sPS + 2 * 16;

    const int t = threadIdx.x, wv = t >> 6, lane = t & 63;
    const int quad = (t >> 4) & 3, m = t & 15;
    const int ch = wv;                    // column half (0: 0-63, 1: 64-127)
    const int g0 = blockIdx.x * GRP;
    const int nbase = (g0 >= NN) ? NN : 0;

    // ---- stage idx, zero geo pads + sRes pad rows ----
    sIdx[t]         = (ushort_t)gidx[(size_t)g0 * KK + t];
    sIdx[t + 128]   = (ushort_t)gidx[(size_t)g0 * KK + t + 128];
    {   // zero shorts 16..31 of every geo row (2 bufs x 32 rows x 2 halves = 128)
        const int b = t >> 6, r = (t >> 1) & 31, h = t & 1;
        *(short8*)&sG[b][r * SG + 16 + h * 8] = (short8)0;
    }
    for (int e = t; e < 8 * SR; e += 128) sRes[8 * SR + e] = 0;   // pad rows 8..15

    // ---- B fragments (4 n-tiles x 5 k-steps) + per-column constants ----
    short8 bWp[5][4];
    #pragma unroll
    for (int ks = 0; ks < 5; ++ks)
        #pragma unroll
        for (int n = 0; n < 4; ++n)
            bWp[ks][n] = ((const short8*)wsWp)[(ks * 4 + quad) * 128 + ch * 64 + n * 16 + m];
    float beffv[4];
    #pragma unroll
    for (int n = 0; n < 4; ++n) beffv[n] = wsBeff[ch * 64 + n * 16 + m];

    __syncthreads();

    // ---- staging mapping: per wave per round: 4 rows x 16 chunks; 4 rounds/point ----
    // round i covers rows i*8 + wv*4 .. +3  (wave-uniform LDS base)
    const int rsub = lane >> 4;           // row within group (0..3)
    const int pc   = lane & 15;           // physical 16B chunk

    float4 fb0[4], fb1[4];                // fallback regs (one 16B bf16 chunk = 8 f32)
    float gcx, gcy, gcz, ggx, ggy, ggz;   // geo regs (lane<16)

    auto issue_dma = [&](int p, int buf) {
        #pragma unroll
        for (int i = 0; i < 4; ++i) {
            const int row = i * 8 + wv * 4 + rsub;
            const int gc  = pc ^ (row & 15);
            const int kn  = nbase + sIdx[p * KK + row];
            const ushort_t* gp = featbf + (size_t)kn * CC + gc * 8;
            short* lp = &sA[buf][(i * 8 + wv * 4) * CC];   // wave-uniform; lane -> +lane*16B
            __builtin_amdgcn_global_load_lds((const __attribute__((address_space(1))) void*)gp,
                                             (__attribute__((address_space(3))) void*)lp, 16, 0, 0);
        }
    };
    auto fb_load = [&](int p) {
        #pragma unroll
        for (int i = 0; i < 4; ++i) {
            const int row = i * 8 + wv * 4 + rsub;
            const int gc  = pc ^ (row & 15);
            const int kn  = nbase + sIdx[p * KK + row];
            const float4* fp = (const float4*)(features + (size_t)kn * CC + gc * 8);
            fb0[i] = fp[0]; fb1[i] = fp[1];
        }
    };
    auto fb_store = [&](int buf) {
        #pragma unroll
        for (int i = 0; i < 4; ++i) {
            const int row = i * 8 + wv * 4 + rsub;
            short8 v;
            v[0]=f2bs(fb0[i].x); v[1]=f2bs(fb0[i].y); v[2]=f2bs(fb0[i].z); v[3]=f2bs(fb0[i].w);
            v[4]=f2bs(fb1[i].x); v[5]=f2bs(fb1[i].y); v[6]=f2bs(fb1[i].z); v[7]=f2bs(fb1[i].w);
            *(short8*)&sA[buf][row * CC + pc * 8] = v;
        }
    };
    auto geo_load = [&](int p) {
        if (lane < 16) {
            const int j  = wv * 16 + lane;          // neighbor row 0..31
            const int pt = g0 + p;
            const int kn = nbase + sIdx[p * KK + j];
            gcx = points[(size_t)pt * 3 + 0]; gcy = points[(size_t)pt * 3 + 1]; gcz = points[(size_t)pt * 3 + 2];
            ggx = points[(size_t)kn * 3 + 0]; ggy = points[(size_t)kn * 3 + 1]; ggz = points[(size_t)kn * 3 + 2];
        }
    };
    auto geo_store = [&](int buf) {
        if (lane < 16) {
            const int j = wv * 16 + lane;
            const float dx = ggx - gcx, dy = ggy - gcy, dz = ggz - gcz;
            const float dist = sqrtf(dx * dx + dy * dy + dz * dz);
            short8 v0, v1 = (short8)0;
            v0[0]=f2bs(gcx); v0[1]=f2bs(gcy); v0[2]=f2bs(gcz);
            v0[3]=f2bs(ggx); v0[4]=f2bs(ggy); v0[5]=f2bs(ggz);
            v0[6]=f2bs(dx);  v0[7]=f2bs(dy);
            v1[0]=f2bs(dz);  v1[1]=f2bs(dist);
            *(short8*)&sG[buf][j * SG + 0] = v0;
            *(short8*)&sG[buf][j * SG + 8] = v1;
        }
    };

    // ---- preload point 0 ----
    if constexpr (DMA) issue_dma(0, 0); else fb_load(0);
    geo_load(0);
    if constexpr (!DMA) fb_store(0);
    geo_store(0);
    __syncthreads();

    // loop-invariant A offsets (shorts)
    int offA[4];
    #pragma unroll
    for (int ks = 0; ks < 4; ++ks) offA[ks] = m * CC + (((ks * 4 + quad) ^ m) * 8);
    const int offG = m * SG + quad * 8;

    for (int p = 0; p < GRP; ++p) {
        const int buf = p & 1, nbuf = buf ^ 1;
        if (p + 1 < GRP) {
            if constexpr (DMA) issue_dma(p + 1, nbuf); else fb_load(p + 1);
            geo_load(p + 1);
        }

        const short* ab = sA[buf];
        const short* ag = sG[buf];
        float4v acc[2][4] = {};    // [mtile][ntile]
        #pragma unroll
        for (int ks = 0; ks < 4; ++ks) {
            const short8 a0 = *(const short8*)(ab + offA[ks]);
            const short8 a1 = *(const short8*)(ab + offA[ks] + 16 * CC);
            #pragma unroll
            for (int n = 0; n < 4; ++n) {
                acc[0][n] = __builtin_amdgcn_mfma_f32_16x16x32_bf16(a0, bWp[ks][n], acc[0][n], 0, 0, 0);
                acc[1][n] = __builtin_amdgcn_mfma_f32_16x16x32_bf16(a1, bWp[ks][n], acc[1][n], 0, 0, 0);
            }
        }
        {
            const short8 a0 = *(const short8*)(ag + offG);
            const short8 a1 = *(const short8*)(ag + offG + 16 * SG);
            #pragma unroll
            for (int n = 0; n < 4; ++n) {
                acc[0][n] = __builtin_amdgcn_mfma_f32_16x16x32_bf16(a0, bWp[4][n], acc[0][n], 0, 0, 0);
                acc[1][n] = __builtin_amdgcn_mfma_f32_16x16x32_bf16(a1, bWp[4][n], acc[1][n], 0, 0, 0);
            }
        }

        if (p + 1 < GRP) {
            if constexpr (!DMA) fb_store(nbuf);
            geo_store(nbuf);
        }

        // ---- relu + max-pool over 32 neighbors, residual, stash res ----
        const int pt = g0 + p;
        #pragma unroll
        for (int n = 0; n < 4; ++n) {
            float v = acc[0][n][0];
            #pragma unroll
            for (int r = 1; r < 4; ++r) v = fmaxf(v, acc[0][n][r]);
            #pragma unroll
            for (int r = 0; r < 4; ++r) v = fmaxf(v, acc[1][n][r]);
            v = fmaxf(v, __shfl_xor(v, 16));
            v = fmaxf(v, __shfl_xor(v, 32));
            v = fmaxf(v + beffv[n], 0.f);
            float fc;
            if constexpr (DMA) fc = bs2f(featbf[(size_t)pt * CC + ch * 64 + n * 16 + m]);
            else               fc = features[(size_t)pt * CC + ch * 64 + n * 16 + m];
            const float res = v + fc;
            if (quad == 0) sRes[p * SR + ch * 64 + n * 16 + m] = f2bs(res);
        }
        __syncthreads();
    }
    // sG no longer read -> safe to reuse as sPS/sPQ.

    // ---- out projection: res(8x128, zero-padded to 16) @ w_out(128x128) ----
    short8 bWo[4][4];
    #pragma unroll
    for (int ks = 0; ks < 4; ++ks)
        #pragma unroll
        for (int n = 0; n < 4; ++n)
            bWo[ks][n] = ((const short8*)wsWo)[(ks * 4 + quad) * 128 + ch * 64 + n * 16 + m];

    const short* rm = sRes + m * SR;
    float4v acc2[4] = {};
    #pragma unroll
    for (int ks = 0; ks < 4; ++ks) {
        const short8 a = *(const short8*)(rm + (ks * 4 + quad) * 8);
        #pragma unroll
        for (int n = 0; n < 4; ++n)
            acc2[n] = __builtin_amdgcn_mfma_f32_16x16x32_bf16(a, bWo[ks][n], acc2[n], 0, 0, 0);
    }

    float boutv[4], lngv[4], lnbv[4];
    #pragma unroll
    for (int n = 0; n < 4; ++n) {
        const int c = ch * 64 + n * 16 + m;
        boutv[n] = b_out[c]; lngv[n] = ln_g[c]; lnbv[n] = ln_b[c];
    }

    // ---- LayerNorm partials: rows R = quad*4+r; wave covers 64 cols ----
    #pragma unroll
    for (int r = 0; r < 4; ++r) {
        float ss = 0.f, qq = 0.f;
        #pragma unroll
        for (int n = 0; n < 4; ++n) {
            const float o = acc2[n][r] + boutv[n];
            ss += o; qq += o * o;
        }
        #pragma unroll
        for (int d = 1; d < 16; d <<= 1) { ss += __shfl_xor(ss, d); qq += __shfl_xor(qq, d); }
        if (m == 0) { sPS[wv * 16 + quad * 4 + r] = ss; sPQ[wv * 16 + quad * 4 + r] = qq; }
    }
    __syncthreads();

    #pragma unroll
    for (int r = 0; r < 4; ++r) {
        const int R = quad * 4 + r;
        if (R < GRP) {
            const float S = sPS[R] + sPS[16 + R];
            const float Q = sPQ[R] + sPQ[16 + R];
            const float mu  = S * (1.f / 128.f);
            const float var = fmaxf(Q * (1.f / 128.f) - mu * mu, 0.f);
            const float rstd = rsqrtf(var + LN_EPS);
            const size_t base = (size_t)(g0 + R) * CC;
            #pragma unroll
            for (int n = 0; n < 4; ++n) {
                const float o = acc2[n][r] + boutv[n];
                out[base + ch * 64 + n * 16 + m] = fmaxf((o - mu) * rstd * lngv[n] + lnbv[n], 0.f);
            }
        }
    }
}

extern "C" void kernel_launch(void* const* d_in, const int* in_sizes, int n_in,
                              void* d_out, int out_size, void* d_ws, size_t ws_size,
                              hipStream_t stream) {
    const float* points   = (const float*)d_in[0];
    const float* features = (const float*)d_in[1];
    const int*   gidx     = (const int*)  d_in[2];
    const float* w_pos    = (const float*)d_in[3];
    const float* b_pos    = (const float*)d_in[4];
    const float* w_gcm    = (const float*)d_in[5];
    const float* b_gcm    = (const float*)d_in[6];
    const float* w_out    = (const float*)d_in[7];
    const float* b_out    = (const float*)d_in[8];
    const float* ln_g     = (const float*)d_in[9];
    const float* ln_b     = (const float*)d_in[10];
    float* out = (float*)d_out;

    char* ws = (char*)d_ws;
    short*    wsWp   = (short*)(ws + WS_WP);
    short*    wsWo   = (short*)(ws + WS_WO);
    float*    wsBeff = (float*)(ws + WS_BE);
    ushort_t* featbf = (ushort_t*)(ws + WS_FB);

    const bool use_dma = (ws_size >= WS_NEED);

    hipLaunchKernelGGL(prep_all, dim3(515), dim3(256), 0, stream,
                       features, w_pos, b_pos, w_gcm, b_gcm, w_out,
                       wsWp, wsWo, wsBeff, featbf, use_dma ? 1 : 0);
    if (use_dma) {
        hipLaunchKernelGGL((bridge_main<1>), dim3(NPTS / GRP), dim3(128), 0, stream,
                           points, features, gidx, wsWp, wsWo, wsBeff, featbf,
                           b_out, ln_g, ln_b, out);
    } else {
        hipLaunchKernelGGL((bridge_main<0>), dim3(NPTS / GRP), dim3(128), 0, stream,
                           points, features, gidx, wsWp, wsWo, wsBeff, featbf,
                           b_out, ln_g, ln_b, out);
    }
}

// Round 12
// 163.163 us; speedup vs baseline: 1.1577x; 1.1577x over previous
//
#include <hip/hip_runtime.h>
#include <hip/hip_bf16.h>
#include <math.h>

typedef __attribute__((ext_vector_type(8))) short short8;
typedef __attribute__((ext_vector_type(4))) float float4v;
typedef unsigned short ushort_t;

constexpr int NPTS = 32768;  // B*N
constexpr int NN   = 16384;  // points per batch
constexpr int KK   = 32;     // neighbors
constexpr int CC   = 128;    // channels
constexpr int GRP  = 16;     // points per block in gather kernel -> grid 2048
constexpr int SR   = 132;    // res LDS row stride (shorts): 264 B -> 2-way banks (free)
#define LN_EPS 1e-5f

// d_ws layout (bytes) — total 8462336 B <= previous footprint (fits)
constexpr size_t WS_PG = 0;        // PG = w_pos@w_gcm: 10*128 f32 = 5120 B
constexpr size_t WS_BE = 5120;     // beff: 128 f32 = 512 B
constexpr size_t WS_WP = 8192;     // w_gcm swizzled bf16 [(k/8)(n)(k%8)]: 32768 B
constexpr size_t WS_WO = 40960;    // w_out swizzled bf16: 32768 B
constexpr size_t WS_FW = 73728;    // FW = F@w_gcm, bf16 [32768][128]: 8388608 B

__device__ __forceinline__ short f2bs(float x) {
    return (short)__builtin_bit_cast(unsigned short, __float2bfloat16(x));
}
__device__ __forceinline__ float bs2f(ushort_t u) {
    return __uint_as_float(((unsigned)u) << 16);
}

// ---------------- prep: PG fold + beff + weight swizzles (13 blocks x 128) ----------------
// blocks 0..9: PG[g][c] (one dot per thread). block 10: beff. block 11: wsWp. block 12: wsWo.
__global__ __launch_bounds__(128) void prep_fold(
    const float* __restrict__ w_pos, const float* __restrict__ b_pos,
    const float* __restrict__ w_gcm, const float* __restrict__ b_gcm,
    const float* __restrict__ w_out,
    float* __restrict__ wsPG, float* __restrict__ wsBeff,
    short* __restrict__ wsWp, short* __restrict__ wsWo)
{
    const int c = threadIdx.x, g = blockIdx.x;
    if (g < 10) {
        float s = 0.f;
        #pragma unroll
        for (int r = 0; r < 128; ++r) s += w_pos[g * 128 + r] * w_gcm[r * 128 + c];
        wsPG[g * 128 + c] = s;
        return;
    }
    if (g == 10) {
        float s = b_gcm[c];
        #pragma unroll
        for (int r = 0; r < 128; ++r) s += b_pos[r] * w_gcm[r * 128 + c];
        wsBeff[c] = s;
        return;
    }
    if (g == 11) {   // w_gcm -> [(k/8)(n)(k%8)] bf16
        #pragma unroll 4
        for (int e = c; e < 16 * 128 * 8; e += 128) {
            const int j = e & 7, n = (e >> 3) & 127, kg = e >> 10;
            wsWp[e] = f2bs(w_gcm[(kg * 8 + j) * 128 + n]);
        }
        return;
    }
    // g == 12: w_out swizzle
    #pragma unroll 4
    for (int e = c; e < 16 * 128 * 8; e += 128) {
        const int j = e & 7, n = (e >> 3) & 127, kg = e >> 10;
        wsWo[e] = f2bs(w_out[(kg * 8 + j) * 128 + n]);
    }
}

// ---------------- FW = F @ w_gcm  (bf16 MFMA, coalesced; 1024 blocks x 256) ----------------
// wave = (row-group rg, col-half ch); wave computes 16 rows x 64 cols.
__global__ __launch_bounds__(256) void fw_gemm(
    const float* __restrict__ F, const short* __restrict__ wsWp,
    ushort_t* __restrict__ fwbf)
{
    const int t = threadIdx.x, wv = t >> 6;
    const int quad = (t >> 4) & 3, m = t & 15;
    const int rg = wv >> 1, ch = wv & 1;
    const int r0 = blockIdx.x * 32 + rg * 16;

    short8 bW[4][4];
    #pragma unroll
    for (int ks = 0; ks < 4; ++ks)
        #pragma unroll
        for (int n = 0; n < 4; ++n)
            bW[ks][n] = ((const short8*)wsWp)[(ks * 4 + quad) * 128 + ch * 64 + n * 16 + m];

    // A fragments: row m of this row-group; k = ks*32 + quad*8 + j  (f32 -> bf16 cvt)
    const float* fr = F + (size_t)(r0 + m) * CC;
    short8 A[4];
    #pragma unroll
    for (int ks = 0; ks < 4; ++ks) {
        const float4 x = *(const float4*)(fr + ks * 32 + quad * 8);
        const float4 y = *(const float4*)(fr + ks * 32 + quad * 8 + 4);
        short8 v;
        v[0]=f2bs(x.x); v[1]=f2bs(x.y); v[2]=f2bs(x.z); v[3]=f2bs(x.w);
        v[4]=f2bs(y.x); v[5]=f2bs(y.y); v[6]=f2bs(y.z); v[7]=f2bs(y.w);
        A[ks] = v;
    }

    float4v acc[4] = {};
    #pragma unroll
    for (int ks = 0; ks < 4; ++ks)
        #pragma unroll
        for (int n = 0; n < 4; ++n)
            acc[n] = __builtin_amdgcn_mfma_f32_16x16x32_bf16(A[ks], bW[ks][n], acc[n], 0, 0, 0);

    // C layout: col = lane&15 (=m), row = quad*4 + r
    #pragma unroll
    for (int n = 0; n < 4; ++n)
        #pragma unroll
        for (int r = 0; r < 4; ++r)
            fwbf[(size_t)(r0 + quad * 4 + r) * CC + ch * 64 + n * 16 + m] =
                (ushort_t)(unsigned short)f2bs(acc[n][r]);
}

// ---------------- main: barrier-free gather-max + MFMA out-proj + LN ----------------
// block 256 thr = two 128-thr sub-blocks; sub s handles points s*8..s*8+7, thread = column c.
__global__ __launch_bounds__(256) void bridge_gather(
    const float* __restrict__ points, const float* __restrict__ features,
    const int*   __restrict__ gidx,
    const float* __restrict__ wsPG, const float* __restrict__ wsBeff,
    const ushort_t* __restrict__ fwbf, const short* __restrict__ wsWo,
    const float* __restrict__ b_out, const float* __restrict__ ln_g,
    const float* __restrict__ ln_b,
    float* __restrict__ out)
{
    __shared__ float4 sND[GRP * KK];      // {nbr xyz, dist} per (p,k): 8192 B; epilogue: sPS/sPQ overlay
    __shared__ int    sOff[GRP * KK];     // byte offset into fwbf: 2048 B
    __shared__ float4 sCen[GRP];          // center xyz per point: 256 B
    __shared__ short  sRes[GRP * SR];     // 4224 B

    float* sPS = (float*)&sND[0];         // [4][GRP] (epilogue only)
    float* sPQ = sPS + 4 * GRP;

    const int t = threadIdx.x, wv = t >> 6;
    const int quad = (t >> 4) & 3, m = t & 15;
    const int sub = t >> 7, c = t & 127;
    const int g0 = blockIdx.x * GRP;
    const int nbase = (g0 >= NN) ? NN : 0;

    // ---- setup: neighbor geometry + gather offsets (2 (p,k) pairs per thread) ----
    #pragma unroll
    for (int e = t; e < GRP * KK; e += 256) {
        const int p = e >> 5;
        const int kn = gidx[(size_t)(g0 + p) * KK + (e & 31)];   // coalesced
        const int row = nbase + kn;
        const float nx = points[(size_t)row * 3 + 0];
        const float ny = points[(size_t)row * 3 + 1];
        const float nz = points[(size_t)row * 3 + 2];
        const float cx = points[(size_t)(g0 + p) * 3 + 0];
        const float cy = points[(size_t)(g0 + p) * 3 + 1];
        const float cz = points[(size_t)(g0 + p) * 3 + 2];
        const float dx = nx - cx, dy = ny - cy, dz = nz - cz;
        sND[e] = make_float4(nx, ny, nz, sqrtf(dx * dx + dy * dy + dz * dz));
        sOff[e] = row << 8;               // row * 128 cols * 2 B
    }
    if (t < GRP) {
        sCen[t] = make_float4(points[(size_t)(g0 + t) * 3 + 0],
                              points[(size_t)(g0 + t) * 3 + 1],
                              points[(size_t)(g0 + t) * 3 + 2], 0.f);
    }

    // ---- per-thread geo weight columns (folded) ----
    float pg[10];
    #pragma unroll
    for (int g = 0; g < 10; ++g) pg[g] = wsPG[g * 128 + c];
    const float pga0 = pg[0] - pg[6], pga1 = pg[1] - pg[7], pga2 = pg[2] - pg[8];
    const float pgb0 = pg[3] + pg[6], pgb1 = pg[4] + pg[7], pgb2 = pg[5] + pg[8];
    const float pgd  = pg[9];
    const float be   = wsBeff[c];

    __syncthreads();

    // ---- gather-max loop: NO barriers, latency hidden by unroll + occupancy ----
    const char* fwc = (const char*)fwbf + c * 2;   // thread's column base
    for (int i = 0; i < GRP / 2; ++i) {
        const int p = sub * (GRP / 2) + i;
        const float4* nd = sND + p * KK;
        const int*    of = sOff + p * KK;
        float acc = -INFINITY;
        #pragma unroll 8
        for (int k = 0; k < KK; ++k) {
            const float4 g = nd[k];                                   // broadcast ds_read_b128
            const float fw = bs2f(*(const ushort_t*)(fwc + of[k]));   // coalesced 2B/lane
            float v = fw + g.w * pgd;
            v = fmaf(g.x, pgb0, v);
            v = fmaf(g.y, pgb1, v);
            v = fmaf(g.z, pgb2, v);
            acc = fmaxf(acc, v);
        }
        const float4 cen = sCen[p];
        const float base = fmaf(cen.x, pga0, fmaf(cen.y, pga1, fmaf(cen.z, pga2, be)));
        const float pooled = fmaxf(acc + base, 0.f);
        const float res = pooled + features[(size_t)(g0 + p) * CC + c];
        sRes[p * SR + c] = f2bs(res);
    }
    __syncthreads();   // sRes complete; sND dead -> sPS/sPQ overlay safe

    // ---- out projection: res(16x128) @ w_out(128x128)  (R10 epilogue) ----
    const int col0 = wv * 32 + m;
    short8 bWo[4][2];
    #pragma unroll
    for (int ks = 0; ks < 4; ++ks)
        #pragma unroll
        for (int ntl = 0; ntl < 2; ++ntl)
            bWo[ks][ntl] = ((const short8*)wsWo)[(ks * 4 + quad) * 128 + col0 + ntl * 16];

    const short* rm = sRes + m * SR;
    float4v acc2[2] = {};
    #pragma unroll
    for (int ks = 0; ks < 4; ++ks) {
        const short8 a = *(const short8*)(rm + ks * 32 + quad * 8);
        acc2[0] = __builtin_amdgcn_mfma_f32_16x16x32_bf16(a, bWo[ks][0], acc2[0], 0, 0, 0);
        acc2[1] = __builtin_amdgcn_mfma_f32_16x16x32_bf16(a, bWo[ks][1], acc2[1], 0, 0, 0);
    }

    const float boutv[2] = { b_out[col0], b_out[col0 + 16] };
    const float lngv[2]  = { ln_g[col0], ln_g[col0 + 16] };
    const float lnbv[2]  = { ln_b[col0], ln_b[col0 + 16] };

    #pragma unroll
    for (int r = 0; r < 4; ++r) {
        const float o0 = acc2[0][r] + boutv[0];
        const float o1 = acc2[1][r] + boutv[1];
        float ss = o0 + o1, qq = o0 * o0 + o1 * o1;
        #pragma unroll
        for (int d = 1; d < 16; d <<= 1) { ss += __shfl_xor(ss, d); qq += __shfl_xor(qq, d); }
        if (m == 0) { sPS[wv * GRP + quad * 4 + r] = ss; sPQ[wv * GRP + quad * 4 + r] = qq; }
    }
    __syncthreads();

    #pragma unroll
    for (int r = 0; r < 4; ++r) {
        const int R = quad * 4 + r;
        const float S = sPS[0 * GRP + R] + sPS[1 * GRP + R] + sPS[2 * GRP + R] + sPS[3 * GRP + R];
        const float Q = sPQ[0 * GRP + R] + sPQ[1 * GRP + R] + sPQ[2 * GRP + R] + sPQ[3 * GRP + R];
        const float mu  = S * (1.f / 128.f);
        const float var = fmaxf(Q * (1.f / 128.f) - mu * mu, 0.f);
        const float rstd = rsqrtf(var + LN_EPS);
        const float o0 = acc2[0][r] + boutv[0];
        const float o1 = acc2[1][r] + boutv[1];
        const size_t base = (size_t)(g0 + R) * CC;
        out[base + col0]      = fmaxf((o0 - mu) * rstd * lngv[0] + lnbv[0], 0.f);
        out[base + col0 + 16] = fmaxf((o1 - mu) * rstd * lngv[1] + lnbv[1], 0.f);
    }
}

extern "C" void kernel_launch(void* const* d_in, const int* in_sizes, int n_in,
                              void* d_out, int out_size, void* d_ws, size_t ws_size,
                              hipStream_t stream) {
    const float* points   = (const float*)d_in[0];
    const float* features = (const float*)d_in[1];
    const int*   gidx     = (const int*)  d_in[2];
    const float* w_pos    = (const float*)d_in[3];
    const float* b_pos    = (const float*)d_in[4];
    const float* w_gcm    = (const float*)d_in[5];
    const float* b_gcm    = (const float*)d_in[6];
    const float* w_out    = (const float*)d_in[7];
    const float* b_out    = (const float*)d_in[8];
    const float* ln_g     = (const float*)d_in[9];
    const float* ln_b     = (const float*)d_in[10];
    float* out = (float*)d_out;

    char* ws = (char*)d_ws;
    float*    wsPG   = (float*)(ws + WS_PG);
    float*    wsBeff = (float*)(ws + WS_BE);
    short*    wsWp   = (short*)(ws + WS_WP);
    short*    wsWo   = (short*)(ws + WS_WO);
    ushort_t* fwbf   = (ushort_t*)(ws + WS_FW);

    hipLaunchKernelGGL(prep_fold, dim3(13), dim3(128), 0, stream,
                       w_pos, b_pos, w_gcm, b_gcm, w_out, wsPG, wsBeff, wsWp, wsWo);
    hipLaunchKernelGGL(fw_gemm, dim3(NPTS / 32), dim3(256), 0, stream,
                       features, wsWp, fwbf);
    hipLaunchKernelGGL(bridge_gather, dim3(NPTS / GRP), dim3(256), 0, stream,
                       points, features, gidx, wsPG, wsBeff, fwbf, wsWo,
                       b_out, ln_g, ln_b, out);
}